// Round 4
// baseline (279.606 us; speedup 1.0000x reference)
//
#include <hip/hip_runtime.h>
#include <math.h>

#define H_ 192
#define W_ 192
#define HW_ 36864
#define C_ 64
#define O_ 64
#define B_ 2
#define K_ 9
#define EPS_ 1e-5f

typedef __attribute__((ext_vector_type(8))) short short8;   // 8 bf16 = 4 VGPR
typedef __attribute__((ext_vector_type(4))) float f32x4;

__device__ __forceinline__ unsigned int f2bf(float f) {
  unsigned int u = __float_as_uint(f);
  u += 0x7FFFu + ((u >> 16) & 1u);   // RTN-even
  return u >> 16;
}
__device__ __forceinline__ unsigned int pk2bf(float lo, float hi) {
  return f2bf(lo) | (f2bf(hi) << 16);
}

// ---------------- K1: depthwise 3x3 conv + bias + BN + ReLU -> h ----------------
__global__ __launch_bounds__(256) void k1_dw(const float* __restrict__ x,
                                             const float* __restrict__ dw_w,
                                             const float* __restrict__ dw_b,
                                             const float* __restrict__ bn_g,
                                             const float* __restrict__ bn_b,
                                             const float* __restrict__ bn_m,
                                             const float* __restrict__ bn_v,
                                             float* __restrict__ h) {
  const int plane = blockIdx.y;                 // b*C + c
  const int c = plane & (C_ - 1);
  const int p = blockIdx.x * 256 + threadIdx.x;
  const int y = p / W_;
  const int xx = p - y * W_;
  const float* xp = x + (size_t)plane * HW_;
  float w[9];
#pragma unroll
  for (int i = 0; i < 9; ++i) w[i] = dw_w[c * 9 + i];
  float s = 0.f;
#pragma unroll
  for (int dy = 0; dy < 3; ++dy) {
    const int yy = y + dy - 1;
    if (yy < 0 || yy >= H_) continue;
#pragma unroll
    for (int dx = 0; dx < 3; ++dx) {
      const int xc = xx + dx - 1;
      if (xc < 0 || xc >= W_) continue;
      s = fmaf(w[dy * 3 + dx], xp[yy * W_ + xc], s);
    }
  }
  const float scale = bn_g[c] * rsqrtf(bn_v[c] + EPS_);
  const float shift = fmaf(dw_b[c] - bn_m[c], scale, bn_b[c]);
  h[(size_t)plane * HW_ + p] = fmaxf(fmaf(s, scale, shift), 0.f);
}

// ---------------- K2: pointwise 64->27 per pixel -> om ----------------
__global__ __launch_bounds__(256) void k2_pw(const float* __restrict__ h,
                                             const float* __restrict__ pw_w,
                                             const float* __restrict__ pw_b,
                                             float* __restrict__ om) {
  __shared__ float wl[C_ * 28];
  const int b = blockIdx.y;
  const int p = blockIdx.x * 256 + threadIdx.x;
  for (int i = threadIdx.x; i < C_ * 28; i += 256) {
    const int c = i / 28, j = i - c * 28;
    wl[i] = (j < 27) ? pw_w[j * C_ + c] : 0.f;
  }
  __syncthreads();
  float s[27];
#pragma unroll
  for (int j = 0; j < 27; ++j) s[j] = 0.f;
  const float* hp = h + (size_t)b * C_ * HW_ + p;
  for (int c = 0; c < C_; ++c) {
    const float hv = hp[(size_t)c * HW_];
    float wv[28];
#pragma unroll
    for (int q = 0; q < 7; ++q)
      *(float4*)&wv[q * 4] = *(const float4*)&wl[c * 28 + q * 4];
#pragma unroll
    for (int j = 0; j < 27; ++j) s[j] = fmaf(hv, wv[j], s[j]);
  }
  float* op = om + (size_t)b * 27 * HW_ + p;
#pragma unroll
  for (int j = 0; j < 27; ++j) op[(size_t)j * HW_] = s[j] + pw_b[j];
}

// ---------------- K0: dcn_w -> wT2[k][o][c] bf16; also zero pstats ----------------
__global__ __launch_bounds__(256) void k0_wt(const float* __restrict__ dcn_w,
                                             unsigned short* __restrict__ wT2,
                                             float* __restrict__ pstats) {
  const int i = blockIdx.x * 256 + threadIdx.x;  // (o*C + c)*9 + k
  if (blockIdx.x == 0) pstats[threadIdx.x] = 0.f;  // 256 = B*O*2
  const int o = i / (C_ * 9);
  const int rem = i - o * (C_ * 9);
  const int c = rem / 9;
  const int kk = rem - c * 9;
  wT2[((size_t)(kk * O_) + o) * C_ + c] = (unsigned short)f2bf(dcn_w[i]);
}

// ---------------- K3: fused deformable gather (fp32) + MFMA bf16 contraction ----
// 64-px tile, 64 o, 256 threads (4 waves). Wave w owns o-strip [w*16, w*16+16).
// LDS bf16 tiles XOR-swizzled (16B blk ^= row&7). Epilogue: LDS transpose ->
// fully-coalesced float4 stores (full 128B lines) + fused IN partial stats.
__global__ __launch_bounds__(256, 4) void k3_dcn(const float* __restrict__ x,
                                                 const float* __restrict__ om,
                                                 const unsigned short* __restrict__ wT2,
                                                 float* __restrict__ pre,
                                                 float* __restrict__ pstats) {
  __shared__ __align__(16) unsigned short smem[8192];  // 16 KB, dual-use
  unsigned short* wlds = smem;         // [o][c] bf16 swz, 8 KB
  unsigned short* vlds = smem + 4096;  // [px][c] bf16 swz, 8 KB

  const int tid = threadIdx.x;
  // bijective XCD swizzle: 1152 blocks = 8 XCD x 144 contiguous tiles
  const int t = (blockIdx.x & 7) * 144 + (blockIdx.x >> 3);
  const int b = t / 576;
  const int p0 = (t - b * 576) * 64;
  const float* xb = x + (size_t)b * C_ * HW_;
  const float* omb = om + (size_t)b * 27 * HW_;

  const int pxi = tid & 63;   // gather pixel
  const int cq = tid >> 6;    // wave id == channel-quarter == o-strip/16
  const int lr = pxi & 15;    // lane&15
  const int lg = pxi >> 4;    // lane>>4 (k-group)
  const int oo0 = cq * 16;

  const int p = p0 + pxi;
  const int y = p / W_;
  const int xx = p - y * W_;

  f32x4 acc[4];
#pragma unroll
  for (int j = 0; j < 4; ++j) acc[j] = (f32x4){0.f, 0.f, 0.f, 0.f};

  // prefetch om for tap 0
  float dyv = omb[p];
  float dxv = omb[(size_t)HW_ + p];
  float mkr = omb[(size_t)18 * HW_ + p];

#pragma unroll 1
  for (int k = 0; k < K_; ++k) {
    // --- issue w-stage loads early (L2-resident, 2 x 16B per thread)
    const uint4* wsrc = (const uint4*)(wT2 + (k << 12));
    const uint4 wv0 = wsrc[tid];
    const uint4 wv1 = wsrc[tid + 256];
    // --- prefetch om for tap k+1
    float ndy = 0.f, ndx = 0.f, nmk = 0.f;
    if (k < K_ - 1) {
      ndy = omb[(size_t)(2 * k + 2) * HW_ + p];
      ndx = omb[(size_t)(2 * k + 3) * HW_ + p];
      nmk = omb[(size_t)(19 + k) * HW_ + p];
    }
    // --- bilinear coords for this tap
    const float mk = 1.f / (1.f + __expf(-mkr));
    const int ky = k / 3;
    const int kx = k - ky * 3;
    const float py = (float)(y + ky - 1) + dyv;
    const float pxf = (float)(xx + kx - 1) + dxv;
    const float y0f = floorf(py), x0f = floorf(pxf);
    const float wy1 = py - y0f, wx1 = pxf - x0f;
    const float wy0 = 1.f - wy1, wx0 = 1.f - wx1;
    const int y0 = (int)y0f, x0i = (int)x0f;
    const int y1 = y0 + 1, x1i = x0i + 1;
    const bool vy0 = (y0 >= 0) & (y0 < H_);
    const bool vy1 = (y1 >= 0) & (y1 < H_);
    const bool vx0 = (x0i >= 0) & (x0i < W_);
    const bool vx1 = (x1i >= 0) & (x1i < W_);
    const int yc0 = min(max(y0, 0), H_ - 1), yc1 = min(max(y1, 0), H_ - 1);
    const int xc0 = min(max(x0i, 0), W_ - 1), xc1 = min(max(x1i, 0), W_ - 1);
    const int i0 = yc0 * W_ + xc0, i1 = yc0 * W_ + xc1;
    const int i2 = yc1 * W_ + xc0, i3 = yc1 * W_ + xc1;
    const float g0 = (vy0 & vx0) ? wy0 * wx0 * mk : 0.f;
    const float g1 = (vy0 & vx1) ? wy0 * wx1 * mk : 0.f;
    const float g2 = (vy1 & vx0) ? wy1 * wx0 * mk : 0.f;
    const float g3 = (vy1 & vx1) ? wy1 * wx1 * mk : 0.f;
    dyv = ndy; dxv = ndx; mkr = nmk;

    // --- gather 16 channels (c = cq*8+i and +32) into regs, before barrier
    float val[16];
#pragma unroll
    for (int i = 0; i < 8; ++i) {
      const int c = (cq << 3) + i;
      const float* pl = xb + (size_t)c * HW_;
      val[i] = fmaf(g0, pl[i0], fmaf(g1, pl[i1], fmaf(g2, pl[i2], g3 * pl[i3])));
      const float* ph = pl + 32 * HW_;
      val[8 + i] = fmaf(g0, ph[i0], fmaf(g1, ph[i1], fmaf(g2, ph[i2], g3 * ph[i3])));
    }

    __syncthreads();  // (A) all waves done MFMA-reading previous tap's LDS
    // --- stage w tap (swizzled 16B blocks): block index i -> row i>>3, blk i&7
    {
      const int r0 = tid >> 3, b0 = tid & 7;
      ((uint4*)wlds)[(r0 << 3) + (b0 ^ (r0 & 7))] = wv0;
      const int r1 = (tid + 256) >> 3;
      ((uint4*)wlds)[(r1 << 3) + (b0 ^ (r1 & 7))] = wv1;
    }
    // --- pack gathered vals to bf16 and write vlds rows (swizzled)
    {
      uint4 pka, pkb;
      pka.x = pk2bf(val[0], val[1]);
      pka.y = pk2bf(val[2], val[3]);
      pka.z = pk2bf(val[4], val[5]);
      pka.w = pk2bf(val[6], val[7]);
      pkb.x = pk2bf(val[8], val[9]);
      pkb.y = pk2bf(val[10], val[11]);
      pkb.z = pk2bf(val[12], val[13]);
      pkb.w = pk2bf(val[14], val[15]);
      const int rsw = pxi & 7;
      ((uint4*)vlds)[(pxi << 3) + (cq ^ rsw)] = pka;
      ((uint4*)vlds)[(pxi << 3) + ((cq + 4) ^ rsw)] = pkb;
    }
    __syncthreads();  // (B) wlds + vlds ready
    // --- MFMA: D[o-strip 16][px 64] += w[o][c] * val[c][px], K=64 in 2 steps
#pragma unroll
    for (int ks = 0; ks < 2; ++ks) {
      const int kb = (ks << 2) + lg;
      const int ra = oo0 + lr;
      const short8 afr = *(const short8*)&((const uint4*)wlds)[(ra << 3) + (kb ^ (ra & 7))];
#pragma unroll
      for (int j = 0; j < 4; ++j) {
        const int rb = (j << 4) + lr;
        const short8 bfr = *(const short8*)&((const uint4*)vlds)[(rb << 3) + (kb ^ (rb & 7))];
        acc[j] = __builtin_amdgcn_mfma_f32_16x16x32_bf16(afr, bfr, acc[j], 0, 0, 0);
      }
    }
  }

  // --- fused instance-norm partial stats (plane = b*64 + oo0 + lg*4 + q)
#pragma unroll
  for (int q = 0; q < 4; ++q) {
    float s = acc[0][q] + acc[1][q] + acc[2][q] + acc[3][q];
    float s2 = acc[0][q] * acc[0][q];
    s2 = fmaf(acc[1][q], acc[1][q], s2);
    s2 = fmaf(acc[2][q], acc[2][q], s2);
    s2 = fmaf(acc[3][q], acc[3][q], s2);
#pragma unroll
    for (int m = 1; m < 16; m <<= 1) {
      s += __shfl_xor(s, m);
      s2 += __shfl_xor(s2, m);
    }
    if (lr == 0) {
      const int plane = (b << 6) + oo0 + (lg << 2) + q;
      atomicAdd(&pstats[plane * 2], s);
      atomicAdd(&pstats[plane * 2 + 1], s2);
    }
  }

  // --- epilogue: transpose through LDS -> coalesced float4 stores
  __syncthreads();  // MFMA reads of smem done everywhere
  float* fsm = (float*)smem;  // [64 o][64 px] f32 = 16 KB
#pragma unroll
  for (int j = 0; j < 4; ++j)
#pragma unroll
    for (int q = 0; q < 4; ++q)
      fsm[(oo0 + (lg << 2) + q) * 64 + (j << 4) + lr] = acc[j][q];
  __syncthreads();
  {
    const float4* fsm4 = (const float4*)fsm;
    float* prebase = pre + (size_t)b * O_ * HW_ + p0;
#pragma unroll
    for (int i = 0; i < 4; ++i) {
      const int f = tid + (i << 8);
      const int o = f >> 4;
      const int px4 = (f & 15) << 2;
      *(float4*)&prebase[(size_t)o * HW_ + px4] = fsm4[f];
    }
  }
}

// ---------------- K4: finalize stats (pstats already full sums) ----------------
__global__ void k4_fin(const float* __restrict__ pstats, float* __restrict__ stats) {
  const int p = threadIdx.x;  // 0..127 = b*O + o
  const float inv = 1.f / (float)HW_;
  const float mu = pstats[p * 2] * inv;
  const float var = fmaxf(fmaf(-mu, mu, pstats[p * 2 + 1] * inv), 0.f);
  stats[p * 2] = mu;
  stats[p * 2 + 1] = rsqrtf(var + EPS_);
}

// ---------------- K5: apply instance norm + ReLU ----------------
__global__ __launch_bounds__(256) void k5_norm(const float* __restrict__ pre,
                                               const float* __restrict__ stats,
                                               float* __restrict__ out) {
  const int i4 = blockIdx.x * 256 + threadIdx.x;
  const int plane = i4 / 9216;
  const float mu = stats[plane * 2];
  const float rs = stats[plane * 2 + 1];
  float4 v = ((const float4*)pre)[i4];
  v.x = fmaxf((v.x - mu) * rs, 0.f);
  v.y = fmaxf((v.y - mu) * rs, 0.f);
  v.z = fmaxf((v.z - mu) * rs, 0.f);
  v.w = fmaxf((v.w - mu) * rs, 0.f);
  ((float4*)out)[i4] = v;
}

extern "C" void kernel_launch(void* const* d_in, const int* in_sizes, int n_in,
                              void* d_out, int out_size, void* d_ws, size_t ws_size,
                              hipStream_t stream) {
  const float* x = (const float*)d_in[0];
  const float* dw_w = (const float*)d_in[1];
  const float* dw_b = (const float*)d_in[2];
  const float* bn_g = (const float*)d_in[3];
  const float* bn_b = (const float*)d_in[4];
  const float* bn_m = (const float*)d_in[5];
  const float* bn_v = (const float*)d_in[6];
  const float* pw_w = (const float*)d_in[7];
  const float* pw_b = (const float*)d_in[8];
  const float* dcn_w = (const float*)d_in[9];
  float* out = (float*)d_out;

  // workspace layout (floats)
  float* ws = (float*)d_ws;
  float* h = ws;                                  // B*C*HW = 4718592 (reused as pre)
  float* om = h + (size_t)B_ * C_ * HW_;          // B*27*HW = 1990656
  unsigned short* wT2 = (unsigned short*)(om + (size_t)B_ * 27 * HW_);  // 36864 u16
  float* pstats = (float*)(wT2 + (size_t)K_ * O_ * C_);  // 256
  float* stats = pstats + 256;                    // 256
  if (ws_size < (size_t)(4718592 + 1990656 + 18432 + 256 + 256) * sizeof(float)) return;
  float* pre = h;  // h is dead after k2; reuse for pre-norm output

  k0_wt<<<dim3(144), dim3(256), 0, stream>>>(dcn_w, wT2, pstats);
  k1_dw<<<dim3(HW_ / 256, B_ * C_), dim3(256), 0, stream>>>(x, dw_w, dw_b, bn_g, bn_b,
                                                            bn_m, bn_v, h);
  k2_pw<<<dim3(HW_ / 256, B_), dim3(256), 0, stream>>>(h, pw_w, pw_b, om);
  k3_dcn<<<dim3(B_ * HW_ / 64), dim3(256), 0, stream>>>(x, om, wT2, pre, pstats);
  k4_fin<<<dim3(1), dim3(128), 0, stream>>>(pstats, stats);
  k5_norm<<<dim3(B_ * O_ * HW_ / 4 / 256), dim3(256), 0, stream>>>(pre, stats, out);
}

// Round 5
// 207.648 us; speedup vs baseline: 1.3465x; 1.3465x over previous
//
#include <hip/hip_runtime.h>
#include <math.h>

#define H_ 192
#define W_ 192
#define HW_ 36864
#define C_ 64
#define O_ 64
#define B_ 2
#define K_ 9
#define EPS_ 1e-5f

typedef __attribute__((ext_vector_type(8))) short short8;   // 8 bf16 = 4 VGPR
typedef __attribute__((ext_vector_type(4))) float f32x4;

__device__ __forceinline__ unsigned int f2bf(float f) {
  unsigned int u = __float_as_uint(f);
  u += 0x7FFFu + ((u >> 16) & 1u);   // RTN-even
  return u >> 16;
}
__device__ __forceinline__ unsigned int pk2bf(float lo, float hi) {
  return f2bf(lo) | (f2bf(hi) << 16);
}

// ---------------- K1: depthwise 3x3 conv + bias + BN + ReLU -> h ----------------
__global__ __launch_bounds__(256) void k1_dw(const float* __restrict__ x,
                                             const float* __restrict__ dw_w,
                                             const float* __restrict__ dw_b,
                                             const float* __restrict__ bn_g,
                                             const float* __restrict__ bn_b,
                                             const float* __restrict__ bn_m,
                                             const float* __restrict__ bn_v,
                                             float* __restrict__ h) {
  const int plane = blockIdx.y;                 // b*C + c
  const int c = plane & (C_ - 1);
  const int p = blockIdx.x * 256 + threadIdx.x;
  const int y = p / W_;
  const int xx = p - y * W_;
  const float* xp = x + (size_t)plane * HW_;
  float w[9];
#pragma unroll
  for (int i = 0; i < 9; ++i) w[i] = dw_w[c * 9 + i];
  float s = 0.f;
#pragma unroll
  for (int dy = 0; dy < 3; ++dy) {
    const int yy = y + dy - 1;
    if (yy < 0 || yy >= H_) continue;
#pragma unroll
    for (int dx = 0; dx < 3; ++dx) {
      const int xc = xx + dx - 1;
      if (xc < 0 || xc >= W_) continue;
      s = fmaf(w[dy * 3 + dx], xp[yy * W_ + xc], s);
    }
  }
  const float scale = bn_g[c] * rsqrtf(bn_v[c] + EPS_);
  const float shift = fmaf(dw_b[c] - bn_m[c], scale, bn_b[c]);
  h[(size_t)plane * HW_ + p] = fmaxf(fmaf(s, scale, shift), 0.f);
}

// ---------------- K2: pointwise 64->27 per pixel -> om ----------------
__global__ __launch_bounds__(256) void k2_pw(const float* __restrict__ h,
                                             const float* __restrict__ pw_w,
                                             const float* __restrict__ pw_b,
                                             float* __restrict__ om) {
  __shared__ float wl[C_ * 28];
  const int b = blockIdx.y;
  const int p = blockIdx.x * 256 + threadIdx.x;
  for (int i = threadIdx.x; i < C_ * 28; i += 256) {
    const int c = i / 28, j = i - c * 28;
    wl[i] = (j < 27) ? pw_w[j * C_ + c] : 0.f;
  }
  __syncthreads();
  float s[27];
#pragma unroll
  for (int j = 0; j < 27; ++j) s[j] = 0.f;
  const float* hp = h + (size_t)b * C_ * HW_ + p;
  for (int c = 0; c < C_; ++c) {
    const float hv = hp[(size_t)c * HW_];
    float wv[28];
#pragma unroll
    for (int q = 0; q < 7; ++q)
      *(float4*)&wv[q * 4] = *(const float4*)&wl[c * 28 + q * 4];
#pragma unroll
    for (int j = 0; j < 27; ++j) s[j] = fmaf(hv, wv[j], s[j]);
  }
  float* op = om + (size_t)b * 27 * HW_ + p;
#pragma unroll
  for (int j = 0; j < 27; ++j) op[(size_t)j * HW_] = s[j] + pw_b[j];
}

// ---------------- K0: dcn_w (O,C,3,3) fp32 -> wT2[k][o][c] bf16 ----------------
__global__ __launch_bounds__(256) void k0_wt(const float* __restrict__ dcn_w,
                                             unsigned short* __restrict__ wT2) {
  const int i = blockIdx.x * 256 + threadIdx.x;  // (o*C + c)*9 + k
  const int o = i / (C_ * 9);
  const int rem = i - o * (C_ * 9);
  const int c = rem / 9;
  const int kk = rem - c * 9;
  wT2[((size_t)(kk * O_) + o) * C_ + c] = (unsigned short)f2bf(dcn_w[i]);
}

// ---------------- K3: fused deformable gather (fp32) + MFMA bf16 contraction ----
// 64-px tile, 64 o, 256 threads (4 waves). Wave w owns o-strip [w*16, w*16+16).
// LDS bf16 tiles XOR-swizzled (16B blk ^= row&7). Epilogue: LDS transpose ->
// fully-coalesced float4 stores (256B aligned chunks). No atomics, no prefetch
// regs (round-4 post-mortem: those two caused the FETCH/WRITE explosion).
__global__ __launch_bounds__(256, 4) void k3_dcn(const float* __restrict__ x,
                                                 const float* __restrict__ om,
                                                 const unsigned short* __restrict__ wT2,
                                                 float* __restrict__ pre) {
  __shared__ __align__(16) unsigned short smem[8192];  // 16 KB, dual-use
  unsigned short* wlds = smem;         // [o][c] bf16 swz, 8 KB
  unsigned short* vlds = smem + 4096;  // [px][c] bf16 swz, 8 KB

  const int tid = threadIdx.x;
  // bijective XCD swizzle: 1152 blocks = 8 XCD x 144 contiguous tiles
  const int t = (blockIdx.x & 7) * 144 + (blockIdx.x >> 3);
  const int b = t / 576;
  const int p0 = (t - b * 576) * 64;
  const float* xb = x + (size_t)b * C_ * HW_;
  const float* omb = om + (size_t)b * 27 * HW_;

  const int pxi = tid & 63;   // gather pixel
  const int cq = tid >> 6;    // wave id == channel-quarter == o-strip/16
  const int lr = pxi & 15;    // lane&15
  const int lg = pxi >> 4;    // lane>>4 (k-group)
  const int oo0 = cq * 16;

  const int p = p0 + pxi;
  const int y = p / W_;
  const int xx = p - y * W_;

  f32x4 acc[4];
#pragma unroll
  for (int j = 0; j < 4; ++j) acc[j] = (f32x4){0.f, 0.f, 0.f, 0.f};

  for (int k = 0; k < K_; ++k) {
    // --- issue w-stage loads early (L2-resident, 2 x 16B per thread)
    const uint4* wsrc = (const uint4*)(wT2 + (k << 12));
    const uint4 wv0 = wsrc[tid];
    const uint4 wv1 = wsrc[tid + 256];
    // --- bilinear coords for this tap (per-thread, redundant x4 per px)
    const float dyv = omb[(size_t)(2 * k) * HW_ + p];
    const float dxv = omb[(size_t)(2 * k + 1) * HW_ + p];
    float mk = omb[(size_t)(18 + k) * HW_ + p];
    mk = 1.f / (1.f + __expf(-mk));
    const int ky = k / 3;
    const int kx = k - ky * 3;
    const float py = (float)(y + ky - 1) + dyv;
    const float pxf = (float)(xx + kx - 1) + dxv;
    const float y0f = floorf(py), x0f = floorf(pxf);
    const float wy1 = py - y0f, wx1 = pxf - x0f;
    const float wy0 = 1.f - wy1, wx0 = 1.f - wx1;
    const int y0 = (int)y0f, x0i = (int)x0f;
    const int y1 = y0 + 1, x1i = x0i + 1;
    const bool vy0 = (y0 >= 0) & (y0 < H_);
    const bool vy1 = (y1 >= 0) & (y1 < H_);
    const bool vx0 = (x0i >= 0) & (x0i < W_);
    const bool vx1 = (x1i >= 0) & (x1i < W_);
    const int yc0 = min(max(y0, 0), H_ - 1), yc1 = min(max(y1, 0), H_ - 1);
    const int xc0 = min(max(x0i, 0), W_ - 1), xc1 = min(max(x1i, 0), W_ - 1);
    const int i0 = yc0 * W_ + xc0, i1 = yc0 * W_ + xc1;
    const int i2 = yc1 * W_ + xc0, i3 = yc1 * W_ + xc1;
    const float g0 = (vy0 & vx0) ? wy0 * wx0 * mk : 0.f;
    const float g1 = (vy0 & vx1) ? wy0 * wx1 * mk : 0.f;
    const float g2 = (vy1 & vx0) ? wy1 * wx0 * mk : 0.f;
    const float g3 = (vy1 & vx1) ? wy1 * wx1 * mk : 0.f;

    // --- gather 16 channels (c = cq*8+i and +32) into regs, before barrier
    float val[16];
#pragma unroll
    for (int i = 0; i < 8; ++i) {
      const int c = (cq << 3) + i;
      const float* pl = xb + (size_t)c * HW_;
      val[i] = fmaf(g0, pl[i0], fmaf(g1, pl[i1], fmaf(g2, pl[i2], g3 * pl[i3])));
      const float* ph = pl + 32 * HW_;
      val[8 + i] = fmaf(g0, ph[i0], fmaf(g1, ph[i1], fmaf(g2, ph[i2], g3 * ph[i3])));
    }

    __syncthreads();  // (A) all waves done MFMA-reading previous tap's LDS
    // --- stage w tap (swizzled 16B blocks): block index i -> row i>>3, blk i&7
    {
      const int r0 = tid >> 3, b0 = tid & 7;
      ((uint4*)wlds)[(r0 << 3) + (b0 ^ (r0 & 7))] = wv0;
      const int r1 = (tid + 256) >> 3;
      ((uint4*)wlds)[(r1 << 3) + (b0 ^ (r1 & 7))] = wv1;
    }
    // --- pack gathered vals to bf16 and write vlds rows (swizzled)
    {
      uint4 pka, pkb;
      pka.x = pk2bf(val[0], val[1]);
      pka.y = pk2bf(val[2], val[3]);
      pka.z = pk2bf(val[4], val[5]);
      pka.w = pk2bf(val[6], val[7]);
      pkb.x = pk2bf(val[8], val[9]);
      pkb.y = pk2bf(val[10], val[11]);
      pkb.z = pk2bf(val[12], val[13]);
      pkb.w = pk2bf(val[14], val[15]);
      const int rsw = pxi & 7;
      ((uint4*)vlds)[(pxi << 3) + (cq ^ rsw)] = pka;
      ((uint4*)vlds)[(pxi << 3) + ((cq + 4) ^ rsw)] = pkb;
    }
    __syncthreads();  // (B) wlds + vlds ready
    // --- MFMA: D[o-strip 16][px 64] += w[o][c] * val[c][px], K=64 in 2 steps
#pragma unroll
    for (int ks = 0; ks < 2; ++ks) {
      const int kb = (ks << 2) + lg;
      const int ra = oo0 + lr;
      const short8 afr = *(const short8*)&((const uint4*)wlds)[(ra << 3) + (kb ^ (ra & 7))];
#pragma unroll
      for (int j = 0; j < 4; ++j) {
        const int rb = (j << 4) + lr;
        const short8 bfr = *(const short8*)&((const uint4*)vlds)[(rb << 3) + (kb ^ (rb & 7))];
        acc[j] = __builtin_amdgcn_mfma_f32_16x16x32_bf16(afr, bfr, acc[j], 0, 0, 0);
      }
    }
  }

  // --- epilogue: transpose through (now dead) LDS -> coalesced float4 stores
  __syncthreads();  // all MFMA reads of smem done
  float* fsm = (float*)smem;  // [64 o][64 px] f32 = 16 KB
#pragma unroll
  for (int j = 0; j < 4; ++j)
#pragma unroll
    for (int q = 0; q < 4; ++q)
      fsm[(oo0 + (lg << 2) + q) * 64 + (j << 4) + lr] = acc[j][q];
  __syncthreads();
  {
    const float4* fsm4 = (const float4*)fsm;
    float* prebase = pre + (size_t)b * O_ * HW_ + p0;
#pragma unroll
    for (int i = 0; i < 4; ++i) {
      const int f = tid + (i << 8);
      const int o = f >> 4;
      const int px4 = (f & 15) << 2;
      *(float4*)&prebase[(size_t)o * HW_ + px4] = fsm4[f];
    }
  }
}

// ---------------- K4: instance-norm stats (two-pass, deterministic) ----------------
__global__ __launch_bounds__(512) void k4_part(const float* __restrict__ pre,
                                               float* __restrict__ pstats) {
  const int plane = blockIdx.x >> 1;
  const int half = blockIdx.x & 1;
  const float4* p4 = (const float4*)(pre + (size_t)plane * HW_) + half * 4608;
  float s = 0.f, s2 = 0.f;
#pragma unroll
  for (int q = 0; q < 9; ++q) {
    const float4 v = p4[q * 512 + threadIdx.x];
    s += v.x + v.y + v.z + v.w;
    s2 = fmaf(v.x, v.x, s2);
    s2 = fmaf(v.y, v.y, s2);
    s2 = fmaf(v.z, v.z, s2);
    s2 = fmaf(v.w, v.w, s2);
  }
#pragma unroll
  for (int off = 32; off > 0; off >>= 1) {
    s += __shfl_down(s, off);
    s2 += __shfl_down(s2, off);
  }
  __shared__ float ls[8], ls2[8];
  const int wid = threadIdx.x >> 6, lane = threadIdx.x & 63;
  if (lane == 0) { ls[wid] = s; ls2[wid] = s2; }
  __syncthreads();
  if (threadIdx.x == 0) {
    float ts = 0.f, ts2 = 0.f;
#pragma unroll
    for (int w = 0; w < 8; ++w) { ts += ls[w]; ts2 += ls2[w]; }
    pstats[blockIdx.x * 2] = ts;
    pstats[blockIdx.x * 2 + 1] = ts2;
  }
}

__global__ void k4_fin(const float* __restrict__ pstats, float* __restrict__ stats) {
  const int p = threadIdx.x;  // 0..127 = b*O + o
  const float s = pstats[(2 * p) * 2] + pstats[(2 * p + 1) * 2];
  const float s2 = pstats[(2 * p) * 2 + 1] + pstats[(2 * p + 1) * 2 + 1];
  const float inv = 1.f / (float)HW_;
  const float mu = s * inv;
  const float var = fmaxf(fmaf(-mu, mu, s2 * inv), 0.f);
  stats[p * 2] = mu;
  stats[p * 2 + 1] = rsqrtf(var + EPS_);
}

// ---------------- K5: apply instance norm + ReLU ----------------
__global__ __launch_bounds__(256) void k5_norm(const float* __restrict__ pre,
                                               const float* __restrict__ stats,
                                               float* __restrict__ out) {
  const int i4 = blockIdx.x * 256 + threadIdx.x;
  const int plane = i4 / 9216;
  const float mu = stats[plane * 2];
  const float rs = stats[plane * 2 + 1];
  float4 v = ((const float4*)pre)[i4];
  v.x = fmaxf((v.x - mu) * rs, 0.f);
  v.y = fmaxf((v.y - mu) * rs, 0.f);
  v.z = fmaxf((v.z - mu) * rs, 0.f);
  v.w = fmaxf((v.w - mu) * rs, 0.f);
  ((float4*)out)[i4] = v;
}

extern "C" void kernel_launch(void* const* d_in, const int* in_sizes, int n_in,
                              void* d_out, int out_size, void* d_ws, size_t ws_size,
                              hipStream_t stream) {
  const float* x = (const float*)d_in[0];
  const float* dw_w = (const float*)d_in[1];
  const float* dw_b = (const float*)d_in[2];
  const float* bn_g = (const float*)d_in[3];
  const float* bn_b = (const float*)d_in[4];
  const float* bn_m = (const float*)d_in[5];
  const float* bn_v = (const float*)d_in[6];
  const float* pw_w = (const float*)d_in[7];
  const float* pw_b = (const float*)d_in[8];
  const float* dcn_w = (const float*)d_in[9];
  float* out = (float*)d_out;

  // workspace layout (floats)
  float* ws = (float*)d_ws;
  float* h = ws;                                  // B*C*HW = 4718592 (reused as pre)
  float* om = h + (size_t)B_ * C_ * HW_;          // B*27*HW = 1990656
  unsigned short* wT2 = (unsigned short*)(om + (size_t)B_ * 27 * HW_);  // 36864 u16
  float* pstats = (float*)(wT2 + (size_t)K_ * O_ * C_);  // 512
  float* stats = pstats + 512;                    // 256
  if (ws_size < (size_t)(4718592 + 1990656 + 18432 + 512 + 256) * sizeof(float)) return;
  float* pre = h;  // h is dead after k2; reuse for pre-norm output

  k0_wt<<<dim3(144), dim3(256), 0, stream>>>(dcn_w, wT2);
  k1_dw<<<dim3(HW_ / 256, B_ * C_), dim3(256), 0, stream>>>(x, dw_w, dw_b, bn_g, bn_b,
                                                            bn_m, bn_v, h);
  k2_pw<<<dim3(HW_ / 256, B_), dim3(256), 0, stream>>>(h, pw_w, pw_b, om);
  k3_dcn<<<dim3(B_ * HW_ / 64), dim3(256), 0, stream>>>(x, om, wT2, pre);
  k4_part<<<dim3(B_ * O_ * 2), dim3(512), 0, stream>>>(pre, pstats);
  k4_fin<<<dim3(1), dim3(128), 0, stream>>>(pstats, stats);
  k5_norm<<<dim3(B_ * O_ * HW_ / 4 / 256), dim3(256), 0, stream>>>(pre, stats, out);
}

// Round 6
// 129.067 us; speedup vs baseline: 2.1664x; 1.6088x over previous
//
#include <hip/hip_runtime.h>
#include <math.h>

#define H_ 192
#define W_ 192
#define HW_ 36864
#define C_ 64
#define O_ 64
#define B_ 2
#define K_ 9
#define EPS_ 1e-5f

typedef __attribute__((ext_vector_type(8))) short short8;   // 8 bf16 = 4 VGPR
typedef __attribute__((ext_vector_type(4))) float f32x4;

__device__ __forceinline__ unsigned int f2bf(float f) {
  unsigned int u = __float_as_uint(f);
  u += 0x7FFFu + ((u >> 16) & 1u);   // RTN-even
  return u >> 16;
}
__device__ __forceinline__ unsigned int pk2bf(float lo, float hi) {
  return f2bf(lo) | (f2bf(hi) << 16);
}
// accumulate 8 bf16 (packed lo|hi per uint) * g into v[0..7]
__device__ __forceinline__ void acc8(const uint4 u, const float g, float* v) {
  v[0] = fmaf(g, __uint_as_float(u.x << 16), v[0]);
  v[1] = fmaf(g, __uint_as_float(u.x & 0xFFFF0000u), v[1]);
  v[2] = fmaf(g, __uint_as_float(u.y << 16), v[2]);
  v[3] = fmaf(g, __uint_as_float(u.y & 0xFFFF0000u), v[3]);
  v[4] = fmaf(g, __uint_as_float(u.z << 16), v[4]);
  v[5] = fmaf(g, __uint_as_float(u.z & 0xFFFF0000u), v[5]);
  v[6] = fmaf(g, __uint_as_float(u.w << 16), v[6]);
  v[7] = fmaf(g, __uint_as_float(u.w & 0xFFFF0000u), v[7]);
}

// ---------------- K1: depthwise 3x3 conv + bias + BN + ReLU -> h ----------------
__global__ __launch_bounds__(256) void k1_dw(const float* __restrict__ x,
                                             const float* __restrict__ dw_w,
                                             const float* __restrict__ dw_b,
                                             const float* __restrict__ bn_g,
                                             const float* __restrict__ bn_b,
                                             const float* __restrict__ bn_m,
                                             const float* __restrict__ bn_v,
                                             float* __restrict__ h) {
  const int plane = blockIdx.y;                 // b*C + c
  const int c = plane & (C_ - 1);
  const int p = blockIdx.x * 256 + threadIdx.x;
  const int y = p / W_;
  const int xx = p - y * W_;
  const float* xp = x + (size_t)plane * HW_;
  float w[9];
#pragma unroll
  for (int i = 0; i < 9; ++i) w[i] = dw_w[c * 9 + i];
  float s = 0.f;
#pragma unroll
  for (int dy = 0; dy < 3; ++dy) {
    const int yy = y + dy - 1;
    if (yy < 0 || yy >= H_) continue;
#pragma unroll
    for (int dx = 0; dx < 3; ++dx) {
      const int xc = xx + dx - 1;
      if (xc < 0 || xc >= W_) continue;
      s = fmaf(w[dy * 3 + dx], xp[yy * W_ + xc], s);
    }
  }
  const float scale = bn_g[c] * rsqrtf(bn_v[c] + EPS_);
  const float shift = fmaf(dw_b[c] - bn_m[c], scale, bn_b[c]);
  h[(size_t)plane * HW_ + p] = fmaxf(fmaf(s, scale, shift), 0.f);
}

// ---------------- K1b: x NCHW fp32 -> xT NHWC bf16 (coalesced reads) ----------------
__global__ __launch_bounds__(256) void k1b_t(const float* __restrict__ x,
                                             unsigned short* __restrict__ xT) {
  const int b = blockIdx.y;
  const int p = blockIdx.x * 256 + threadIdx.x;
  const float* xp = x + (size_t)b * C_ * HW_ + p;
  uint4* dst = (uint4*)xT + (((size_t)b * HW_ + p) << 3);
#pragma unroll
  for (int cc = 0; cc < 8; ++cc) {
    uint4 u;
    u.x = pk2bf(xp[(size_t)(cc * 8 + 0) * HW_], xp[(size_t)(cc * 8 + 1) * HW_]);
    u.y = pk2bf(xp[(size_t)(cc * 8 + 2) * HW_], xp[(size_t)(cc * 8 + 3) * HW_]);
    u.z = pk2bf(xp[(size_t)(cc * 8 + 4) * HW_], xp[(size_t)(cc * 8 + 5) * HW_]);
    u.w = pk2bf(xp[(size_t)(cc * 8 + 6) * HW_], xp[(size_t)(cc * 8 + 7) * HW_]);
    dst[cc] = u;
  }
}

// ---------------- K2: pointwise 64->27 per pixel -> om ----------------
__global__ __launch_bounds__(256) void k2_pw(const float* __restrict__ h,
                                             const float* __restrict__ pw_w,
                                             const float* __restrict__ pw_b,
                                             float* __restrict__ om) {
  __shared__ float wl[C_ * 28];
  const int b = blockIdx.y;
  const int p = blockIdx.x * 256 + threadIdx.x;
  for (int i = threadIdx.x; i < C_ * 28; i += 256) {
    const int c = i / 28, j = i - c * 28;
    wl[i] = (j < 27) ? pw_w[j * C_ + c] : 0.f;
  }
  __syncthreads();
  float s[27];
#pragma unroll
  for (int j = 0; j < 27; ++j) s[j] = 0.f;
  const float* hp = h + (size_t)b * C_ * HW_ + p;
  for (int c = 0; c < C_; ++c) {
    const float hv = hp[(size_t)c * HW_];
    float wv[28];
#pragma unroll
    for (int q = 0; q < 7; ++q)
      *(float4*)&wv[q * 4] = *(const float4*)&wl[c * 28 + q * 4];
#pragma unroll
    for (int j = 0; j < 27; ++j) s[j] = fmaf(hv, wv[j], s[j]);
  }
  float* op = om + (size_t)b * 27 * HW_ + p;
#pragma unroll
  for (int j = 0; j < 27; ++j) op[(size_t)j * HW_] = s[j] + pw_b[j];
}

// ---------------- K0: dcn_w (O,C,3,3) fp32 -> wT2[k][o][c] bf16 ----------------
__global__ __launch_bounds__(256) void k0_wt(const float* __restrict__ dcn_w,
                                             unsigned short* __restrict__ wT2) {
  const int i = blockIdx.x * 256 + threadIdx.x;  // (o*C + c)*9 + k
  const int o = i / (C_ * 9);
  const int rem = i - o * (C_ * 9);
  const int c = rem / 9;
  const int kk = rem - c * 9;
  wT2[((size_t)(kk * O_) + o) * C_ + c] = (unsigned short)f2bf(dcn_w[i]);
}

// ---------------- K3: fused deformable gather (bf16 NHWC) + MFMA contraction ----
// 64-px tile, 64 o, 256 threads (4 waves). Wave cq handles channels {8cq..8cq+7,
// 32+8cq..32+8cq+7} for its pixel (2 uint4 = 16ch per corner) and o-strip cq*16.
// VMEM per thread-tap: 8 x-loads + 3 om + 2 wT2 (was 69 -> 5x fewer).
__global__ __launch_bounds__(256, 4) void k3_dcn(const unsigned short* __restrict__ xT,
                                                 const float* __restrict__ om,
                                                 const unsigned short* __restrict__ wT2,
                                                 float* __restrict__ pre) {
  __shared__ __align__(16) unsigned short smem[8192];  // 16 KB, dual-use
  unsigned short* wlds = smem;         // [o][c] bf16 swz, 8 KB
  unsigned short* vlds = smem + 4096;  // [px][c] bf16 swz, 8 KB

  const int tid = threadIdx.x;
  // bijective XCD swizzle: 1152 blocks = 8 XCD x 144 contiguous tiles
  const int t = (blockIdx.x & 7) * 144 + (blockIdx.x >> 3);
  const int b = t / 576;
  const int p0 = (t - b * 576) * 64;
  const uint4* xt = (const uint4*)xT + (((size_t)b * HW_) << 3);
  const float* omb = om + (size_t)b * 27 * HW_;

  const int pxi = tid & 63;   // gather pixel
  const int cq = tid >> 6;    // wave id == channel-slot == o-strip/16
  const int lr = pxi & 15;    // lane&15
  const int lg = pxi >> 4;    // lane>>4 (k-group)
  const int oo0 = cq * 16;

  const int p = p0 + pxi;
  const int y = p / W_;
  const int xx = p - y * W_;

  f32x4 acc[4];
#pragma unroll
  for (int j = 0; j < 4; ++j) acc[j] = (f32x4){0.f, 0.f, 0.f, 0.f};

  for (int k = 0; k < K_; ++k) {
    // --- issue w-stage loads early (L2-resident, 2 x 16B per thread)
    const uint4* wsrc = (const uint4*)(wT2 + (k << 12));
    const uint4 wv0 = wsrc[tid];
    const uint4 wv1 = wsrc[tid + 256];
    // --- bilinear coords for this tap (per-thread, redundant x4 per px)
    const float dyv = omb[(size_t)(2 * k) * HW_ + p];
    const float dxv = omb[(size_t)(2 * k + 1) * HW_ + p];
    float mk = omb[(size_t)(18 + k) * HW_ + p];
    mk = 1.f / (1.f + __expf(-mk));
    const int ky = k / 3;
    const int kx = k - ky * 3;
    const float py = (float)(y + ky - 1) + dyv;
    const float pxf = (float)(xx + kx - 1) + dxv;
    const float y0f = floorf(py), x0f = floorf(pxf);
    const float wy1 = py - y0f, wx1 = pxf - x0f;
    const float wy0 = 1.f - wy1, wx0 = 1.f - wx1;
    const int y0 = (int)y0f, x0i = (int)x0f;
    const int y1 = y0 + 1, x1i = x0i + 1;
    const bool vy0 = (y0 >= 0) & (y0 < H_);
    const bool vy1 = (y1 >= 0) & (y1 < H_);
    const bool vx0 = (x0i >= 0) & (x0i < W_);
    const bool vx1 = (x1i >= 0) & (x1i < W_);
    const int yc0 = min(max(y0, 0), H_ - 1), yc1 = min(max(y1, 0), H_ - 1);
    const int xc0 = min(max(x0i, 0), W_ - 1), xc1 = min(max(x1i, 0), W_ - 1);
    const int i0 = yc0 * W_ + xc0, i1 = yc0 * W_ + xc1;
    const int i2 = yc1 * W_ + xc0, i3 = yc1 * W_ + xc1;
    const float g0 = (vy0 & vx0) ? wy0 * wx0 * mk : 0.f;
    const float g1 = (vy0 & vx1) ? wy0 * wx1 * mk : 0.f;
    const float g2 = (vy1 & vx0) ? wy1 * wx0 * mk : 0.f;
    const float g3 = (vy1 & vx1) ? wy1 * wx1 * mk : 0.f;

    // --- vectorized gather: 2 uint4 (16 ch) per corner, 8 loads total
    const uint4* c0p = &xt[((size_t)i0 << 3) + cq];
    const uint4* c1p = &xt[((size_t)i1 << 3) + cq];
    const uint4* c2p = &xt[((size_t)i2 << 3) + cq];
    const uint4* c3p = &xt[((size_t)i3 << 3) + cq];
    const uint4 a0 = c0p[0], b0 = c0p[4];
    const uint4 a1 = c1p[0], b1 = c1p[4];
    const uint4 a2 = c2p[0], b2 = c2p[4];
    const uint4 a3 = c3p[0], b3 = c3p[4];
    float val[16];
#pragma unroll
    for (int i = 0; i < 16; ++i) val[i] = 0.f;
    acc8(a0, g0, val);  acc8(b0, g0, val + 8);
    acc8(a1, g1, val);  acc8(b1, g1, val + 8);
    acc8(a2, g2, val);  acc8(b2, g2, val + 8);
    acc8(a3, g3, val);  acc8(b3, g3, val + 8);

    __syncthreads();  // (A) all waves done MFMA-reading previous tap's LDS
    // --- stage w tap (swizzled 16B blocks): block index i -> row i>>3, blk i&7
    {
      const int r0 = tid >> 3, b0i = tid & 7;
      ((uint4*)wlds)[(r0 << 3) + (b0i ^ (r0 & 7))] = wv0;
      const int r1 = (tid + 256) >> 3;
      ((uint4*)wlds)[(r1 << 3) + (b0i ^ (r1 & 7))] = wv1;
    }
    // --- pack gathered vals to bf16 and write vlds rows (swizzled)
    {
      uint4 pka, pkb;
      pka.x = pk2bf(val[0], val[1]);
      pka.y = pk2bf(val[2], val[3]);
      pka.z = pk2bf(val[4], val[5]);
      pka.w = pk2bf(val[6], val[7]);
      pkb.x = pk2bf(val[8], val[9]);
      pkb.y = pk2bf(val[10], val[11]);
      pkb.z = pk2bf(val[12], val[13]);
      pkb.w = pk2bf(val[14], val[15]);
      const int rsw = pxi & 7;
      ((uint4*)vlds)[(pxi << 3) + (cq ^ rsw)] = pka;
      ((uint4*)vlds)[(pxi << 3) + ((cq + 4) ^ rsw)] = pkb;
    }
    __syncthreads();  // (B) wlds + vlds ready
    // --- MFMA: D[o-strip 16][px 64] += w[o][c] * val[c][px], K=64 in 2 steps
#pragma unroll
    for (int ks = 0; ks < 2; ++ks) {
      const int kb = (ks << 2) + lg;
      const int ra = oo0 + lr;
      const short8 afr = *(const short8*)&((const uint4*)wlds)[(ra << 3) + (kb ^ (ra & 7))];
#pragma unroll
      for (int j = 0; j < 4; ++j) {
        const int rb = (j << 4) + lr;
        const short8 bfr = *(const short8*)&((const uint4*)vlds)[(rb << 3) + (kb ^ (rb & 7))];
        acc[j] = __builtin_amdgcn_mfma_f32_16x16x32_bf16(afr, bfr, acc[j], 0, 0, 0);
      }
    }
  }

  // --- epilogue: transpose through (now dead) LDS -> coalesced float4 stores
  __syncthreads();  // all MFMA reads of smem done
  float* fsm = (float*)smem;  // [64 o][64 px] f32 = 16 KB
#pragma unroll
  for (int j = 0; j < 4; ++j)
#pragma unroll
    for (int q = 0; q < 4; ++q)
      fsm[(oo0 + (lg << 2) + q) * 64 + (j << 4) + lr] = acc[j][q];
  __syncthreads();
  {
    const float4* fsm4 = (const float4*)fsm;
    float* prebase = pre + (size_t)b * O_ * HW_ + p0;
#pragma unroll
    for (int i = 0; i < 4; ++i) {
      const int f = tid + (i << 8);
      const int o = f >> 4;
      const int px4 = (f & 15) << 2;
      *(float4*)&prebase[(size_t)o * HW_ + px4] = fsm4[f];
    }
  }
}

// ---------------- K4: instance-norm stats (two-pass, deterministic) ----------------
__global__ __launch_bounds__(512) void k4_part(const float* __restrict__ pre,
                                               float* __restrict__ pstats) {
  const int plane = blockIdx.x >> 1;
  const int half = blockIdx.x & 1;
  const float4* p4 = (const float4*)(pre + (size_t)plane * HW_) + half * 4608;
  float s = 0.f, s2 = 0.f;
#pragma unroll
  for (int q = 0; q < 9; ++q) {
    const float4 v = p4[q * 512 + threadIdx.x];
    s += v.x + v.y + v.z + v.w;
    s2 = fmaf(v.x, v.x, s2);
    s2 = fmaf(v.y, v.y, s2);
    s2 = fmaf(v.z, v.z, s2);
    s2 = fmaf(v.w, v.w, s2);
  }
#pragma unroll
  for (int off = 32; off > 0; off >>= 1) {
    s += __shfl_down(s, off);
    s2 += __shfl_down(s2, off);
  }
  __shared__ float ls[8], ls2[8];
  const int wid = threadIdx.x >> 6, lane = threadIdx.x & 63;
  if (lane == 0) { ls[wid] = s; ls2[wid] = s2; }
  __syncthreads();
  if (threadIdx.x == 0) {
    float ts = 0.f, ts2 = 0.f;
#pragma unroll
    for (int w = 0; w < 8; ++w) { ts += ls[w]; ts2 += ls2[w]; }
    pstats[blockIdx.x * 2] = ts;
    pstats[blockIdx.x * 2 + 1] = ts2;
  }
}

__global__ void k4_fin(const float* __restrict__ pstats, float* __restrict__ stats) {
  const int p = threadIdx.x;  // 0..127 = b*O + o
  const float s = pstats[(2 * p) * 2] + pstats[(2 * p + 1) * 2];
  const float s2 = pstats[(2 * p) * 2 + 1] + pstats[(2 * p + 1) * 2 + 1];
  const float inv = 1.f / (float)HW_;
  const float mu = s * inv;
  const float var = fmaxf(fmaf(-mu, mu, s2 * inv), 0.f);
  stats[p * 2] = mu;
  stats[p * 2 + 1] = rsqrtf(var + EPS_);
}

// ---------------- K5: apply instance norm + ReLU ----------------
__global__ __launch_bounds__(256) void k5_norm(const float* __restrict__ pre,
                                               const float* __restrict__ stats,
                                               float* __restrict__ out) {
  const int i4 = blockIdx.x * 256 + threadIdx.x;
  const int plane = i4 / 9216;
  const float mu = stats[plane * 2];
  const float rs = stats[plane * 2 + 1];
  float4 v = ((const float4*)pre)[i4];
  v.x = fmaxf((v.x - mu) * rs, 0.f);
  v.y = fmaxf((v.y - mu) * rs, 0.f);
  v.z = fmaxf((v.z - mu) * rs, 0.f);
  v.w = fmaxf((v.w - mu) * rs, 0.f);
  ((float4*)out)[i4] = v;
}

extern "C" void kernel_launch(void* const* d_in, const int* in_sizes, int n_in,
                              void* d_out, int out_size, void* d_ws, size_t ws_size,
                              hipStream_t stream) {
  const float* x = (const float*)d_in[0];
  const float* dw_w = (const float*)d_in[1];
  const float* dw_b = (const float*)d_in[2];
  const float* bn_g = (const float*)d_in[3];
  const float* bn_b = (const float*)d_in[4];
  const float* bn_m = (const float*)d_in[5];
  const float* bn_v = (const float*)d_in[6];
  const float* pw_w = (const float*)d_in[7];
  const float* pw_b = (const float*)d_in[8];
  const float* dcn_w = (const float*)d_in[9];
  float* out = (float*)d_out;

  // workspace layout (floats)
  float* ws = (float*)d_ws;
  float* h = ws;                                  // B*C*HW = 4718592 (reused as pre)
  float* om = h + (size_t)B_ * C_ * HW_;          // B*27*HW = 1990656
  unsigned short* wT2 = (unsigned short*)(om + (size_t)B_ * 27 * HW_);  // 36864 u16
  float* pstats = (float*)(wT2 + (size_t)K_ * O_ * C_);  // 512
  float* stats = pstats + 512;                    // 256
  if (ws_size < (size_t)(4718592 + 1990656 + 18432 + 512 + 256) * sizeof(float)) return;
  float* pre = h;  // h is dead after k2; reuse for pre-norm output
  // xT (NHWC bf16, 9.4 MB) lives in d_out: fully overwritten by k5 afterwards.
  unsigned short* xT = (unsigned short*)d_out;

  k0_wt<<<dim3(144), dim3(256), 0, stream>>>(dcn_w, wT2);
  k1b_t<<<dim3(HW_ / 256, B_), dim3(256), 0, stream>>>(x, xT);
  k1_dw<<<dim3(HW_ / 256, B_ * C_), dim3(256), 0, stream>>>(x, dw_w, dw_b, bn_g, bn_b,
                                                            bn_m, bn_v, h);
  k2_pw<<<dim3(HW_ / 256, B_), dim3(256), 0, stream>>>(h, pw_w, pw_b, om);
  k3_dcn<<<dim3(B_ * HW_ / 64), dim3(256), 0, stream>>>(xT, om, wT2, pre);
  k4_part<<<dim3(B_ * O_ * 2), dim3(512), 0, stream>>>(pre, pstats);
  k4_fin<<<dim3(1), dim3(128), 0, stream>>>(pstats, stats);
  k5_norm<<<dim3(B_ * O_ * HW_ / 4 / 256), dim3(256), 0, stream>>>(pre, stats, out);
}

// Round 7
// 106.688 us; speedup vs baseline: 2.6208x; 1.2098x over previous
//
#include <hip/hip_runtime.h>
#include <math.h>

#define H_ 192
#define W_ 192
#define HW_ 36864
#define C_ 64
#define O_ 64
#define B_ 2
#define K_ 9
#define EPS_ 1e-5f

typedef __attribute__((ext_vector_type(8))) short short8;   // 8 bf16 = 4 VGPR
typedef __attribute__((ext_vector_type(4))) float f32x4;

__device__ __forceinline__ unsigned int f2bf(float f) {
  unsigned int u = __float_as_uint(f);
  u += 0x7FFFu + ((u >> 16) & 1u);   // RTN-even
  return u >> 16;
}
__device__ __forceinline__ unsigned int pk2bf(float lo, float hi) {
  return f2bf(lo) | (f2bf(hi) << 16);
}
// accumulate 8 bf16 (packed lo|hi per uint) * g into v[0..7]
__device__ __forceinline__ void acc8(const uint4 u, const float g, float* v) {
  v[0] = fmaf(g, __uint_as_float(u.x << 16), v[0]);
  v[1] = fmaf(g, __uint_as_float(u.x & 0xFFFF0000u), v[1]);
  v[2] = fmaf(g, __uint_as_float(u.y << 16), v[2]);
  v[3] = fmaf(g, __uint_as_float(u.y & 0xFFFF0000u), v[3]);
  v[4] = fmaf(g, __uint_as_float(u.z << 16), v[4]);
  v[5] = fmaf(g, __uint_as_float(u.z & 0xFFFF0000u), v[5]);
  v[6] = fmaf(g, __uint_as_float(u.w << 16), v[6]);
  v[7] = fmaf(g, __uint_as_float(u.w & 0xFFFF0000u), v[7]);
}

// ---------------- K1: depthwise 3x3 conv + bias + BN + ReLU -> h ----------------
__global__ __launch_bounds__(256) void k1_dw(const float* __restrict__ x,
                                             const float* __restrict__ dw_w,
                                             const float* __restrict__ dw_b,
                                             const float* __restrict__ bn_g,
                                             const float* __restrict__ bn_b,
                                             const float* __restrict__ bn_m,
                                             const float* __restrict__ bn_v,
                                             float* __restrict__ h) {
  const int plane = blockIdx.y;                 // b*C + c
  const int c = plane & (C_ - 1);
  const int p = blockIdx.x * 256 + threadIdx.x;
  const int y = p / W_;
  const int xx = p - y * W_;
  const float* xp = x + (size_t)plane * HW_;
  float w[9];
#pragma unroll
  for (int i = 0; i < 9; ++i) w[i] = dw_w[c * 9 + i];
  float s = 0.f;
#pragma unroll
  for (int dy = 0; dy < 3; ++dy) {
    const int yy = y + dy - 1;
    if (yy < 0 || yy >= H_) continue;
#pragma unroll
    for (int dx = 0; dx < 3; ++dx) {
      const int xc = xx + dx - 1;
      if (xc < 0 || xc >= W_) continue;
      s = fmaf(w[dy * 3 + dx], xp[yy * W_ + xc], s);
    }
  }
  const float scale = bn_g[c] * rsqrtf(bn_v[c] + EPS_);
  const float shift = fmaf(dw_b[c] - bn_m[c], scale, bn_b[c]);
  h[(size_t)plane * HW_ + p] = fmaxf(fmaf(s, scale, shift), 0.f);
}

// ---------------- K1b: x NCHW fp32 -> xR[b][y][cg][x][8ch] bf16 ----------------
// gather-coherent layout: one 16B chunk = 8 channels of one pixel; consecutive x
// -> consecutive 16B chunks, so a wave of consecutive pixels strides 16B not 128B.
__global__ __launch_bounds__(256) void k1b_t(const float* __restrict__ x,
                                             unsigned short* __restrict__ xR) {
  const int b = blockIdx.y;
  const int p = blockIdx.x * 256 + threadIdx.x;
  const int y = p / W_;
  const int xx = p - y * W_;
  const float* xp = x + (size_t)b * C_ * HW_ + p;
  uint4* dst = (uint4*)xR + (size_t)b * HW_ * 8;
#pragma unroll
  for (int cc = 0; cc < 8; ++cc) {
    uint4 u;
    u.x = pk2bf(xp[(size_t)(cc * 8 + 0) * HW_], xp[(size_t)(cc * 8 + 1) * HW_]);
    u.y = pk2bf(xp[(size_t)(cc * 8 + 2) * HW_], xp[(size_t)(cc * 8 + 3) * HW_]);
    u.z = pk2bf(xp[(size_t)(cc * 8 + 4) * HW_], xp[(size_t)(cc * 8 + 5) * HW_]);
    u.w = pk2bf(xp[(size_t)(cc * 8 + 6) * HW_], xp[(size_t)(cc * 8 + 7) * HW_]);
    dst[(y * 8 + cc) * W_ + xx] = u;
  }
}

// ---------------- K2: pointwise 64->27 per pixel -> om ----------------
__global__ __launch_bounds__(256) void k2_pw(const float* __restrict__ h,
                                             const float* __restrict__ pw_w,
                                             const float* __restrict__ pw_b,
                                             float* __restrict__ om) {
  __shared__ float wl[C_ * 28];
  const int b = blockIdx.y;
  const int p = blockIdx.x * 256 + threadIdx.x;
  for (int i = threadIdx.x; i < C_ * 28; i += 256) {
    const int c = i / 28, j = i - c * 28;
    wl[i] = (j < 27) ? pw_w[j * C_ + c] : 0.f;
  }
  __syncthreads();
  float s[27];
#pragma unroll
  for (int j = 0; j < 27; ++j) s[j] = 0.f;
  const float* hp = h + (size_t)b * C_ * HW_ + p;
  for (int c = 0; c < C_; ++c) {
    const float hv = hp[(size_t)c * HW_];
    float wv[28];
#pragma unroll
    for (int q = 0; q < 7; ++q)
      *(float4*)&wv[q * 4] = *(const float4*)&wl[c * 28 + q * 4];
#pragma unroll
    for (int j = 0; j < 27; ++j) s[j] = fmaf(hv, wv[j], s[j]);
  }
  float* op = om + (size_t)b * 27 * HW_ + p;
#pragma unroll
  for (int j = 0; j < 27; ++j) op[(size_t)j * HW_] = s[j] + pw_b[j];
}

// ---------------- K0: dcn_w (O,C,3,3) fp32 -> wT2[k][o][c] bf16 ----------------
__global__ __launch_bounds__(256) void k0_wt(const float* __restrict__ dcn_w,
                                             unsigned short* __restrict__ wT2) {
  const int i = blockIdx.x * 256 + threadIdx.x;  // (o*C + c)*9 + k
  const int o = i / (C_ * 9);
  const int rem = i - o * (C_ * 9);
  const int c = rem / 9;
  const int kk = rem - c * 9;
  wT2[((size_t)(kk * O_) + o) * C_ + c] = (unsigned short)f2bf(dcn_w[i]);
}

// ---------------- K3: fused deformable gather (bf16) + MFMA contraction ----
// 64-px tile, 64 o, 256 threads (4 waves). Wave cq handles channel-groups
// {cq, cq+4} (8 ch each) for its pixel and o-strip cq*16. Gather addresses are
// x-coherent (16B lane stride). Epilogue: register-only IN partial stats
// (no atomics) + LDS-transpose coalesced float4 stores.
__global__ __launch_bounds__(256, 4) void k3_dcn(const unsigned short* __restrict__ xR,
                                                 const float* __restrict__ om,
                                                 const unsigned short* __restrict__ wT2,
                                                 float* __restrict__ pre,
                                                 float* __restrict__ pstats2) {
  __shared__ __align__(16) unsigned short smem[8192];  // 16 KB, dual-use
  unsigned short* wlds = smem;         // [o][c] bf16 swz, 8 KB
  unsigned short* vlds = smem + 4096;  // [px][c] bf16 swz, 8 KB

  const int tid = threadIdx.x;
  // bijective XCD swizzle: 1152 blocks = 8 XCD x 144 contiguous tiles
  const int t = (blockIdx.x & 7) * 144 + (blockIdx.x >> 3);
  const int b = t / 576;
  const int p0 = (t - b * 576) * 64;
  const uint4* xr = (const uint4*)xR + (size_t)b * HW_ * 8;
  const float* omb = om + (size_t)b * 27 * HW_;

  const int pxi = tid & 63;   // gather pixel
  const int cq = tid >> 6;    // wave id == channel-group slot == o-strip/16
  const int lr = pxi & 15;    // lane&15
  const int lg = pxi >> 4;    // lane>>4 (k-group)
  const int oo0 = cq * 16;

  const int p = p0 + pxi;
  const int y = p / W_;
  const int xx = p - y * W_;

  f32x4 acc[4];
#pragma unroll
  for (int j = 0; j < 4; ++j) acc[j] = (f32x4){0.f, 0.f, 0.f, 0.f};

  for (int k = 0; k < K_; ++k) {
    // --- issue w-stage loads early (L2-resident, 2 x 16B per thread)
    const uint4* wsrc = (const uint4*)(wT2 + (k << 12));
    const uint4 wv0 = wsrc[tid];
    const uint4 wv1 = wsrc[tid + 256];
    // --- bilinear coords for this tap (per-thread, redundant x4 per px)
    const float dyv = omb[(size_t)(2 * k) * HW_ + p];
    const float dxv = omb[(size_t)(2 * k + 1) * HW_ + p];
    float mk = omb[(size_t)(18 + k) * HW_ + p];
    mk = 1.f / (1.f + __expf(-mk));
    const int ky = k / 3;
    const int kx = k - ky * 3;
    const float py = (float)(y + ky - 1) + dyv;
    const float pxf = (float)(xx + kx - 1) + dxv;
    const float y0f = floorf(py), x0f = floorf(pxf);
    const float wy1 = py - y0f, wx1 = pxf - x0f;
    const float wy0 = 1.f - wy1, wx0 = 1.f - wx1;
    const int y0 = (int)y0f, x0i = (int)x0f;
    const int y1 = y0 + 1, x1i = x0i + 1;
    const bool vy0 = (y0 >= 0) & (y0 < H_);
    const bool vy1 = (y1 >= 0) & (y1 < H_);
    const bool vx0 = (x0i >= 0) & (x0i < W_);
    const bool vx1 = (x1i >= 0) & (x1i < W_);
    const int yc0 = min(max(y0, 0), H_ - 1), yc1 = min(max(y1, 0), H_ - 1);
    const int xc0 = min(max(x0i, 0), W_ - 1), xc1 = min(max(x1i, 0), W_ - 1);
    const float g0 = (vy0 & vx0) ? wy0 * wx0 * mk : 0.f;
    const float g1 = (vy0 & vx1) ? wy0 * wx1 * mk : 0.f;
    const float g2 = (vy1 & vx0) ? wy1 * wx0 * mk : 0.f;
    const float g3 = (vy1 & vx1) ? wy1 * wx1 * mk : 0.f;

    // --- x-coherent gather: 8 x 16B loads (4 corners x 2 channel-groups)
    const int ry0 = yc0 * (8 * W_), ry1 = yc1 * (8 * W_);
    const int ca = cq * W_, cb = (cq + 4) * W_;
    const uint4 a0 = xr[ry0 + ca + xc0], b0v = xr[ry0 + cb + xc0];
    const uint4 a1 = xr[ry0 + ca + xc1], b1v = xr[ry0 + cb + xc1];
    const uint4 a2 = xr[ry1 + ca + xc0], b2v = xr[ry1 + cb + xc0];
    const uint4 a3 = xr[ry1 + ca + xc1], b3v = xr[ry1 + cb + xc1];
    float val[16];
#pragma unroll
    for (int i = 0; i < 16; ++i) val[i] = 0.f;
    acc8(a0, g0, val);  acc8(b0v, g0, val + 8);
    acc8(a1, g1, val);  acc8(b1v, g1, val + 8);
    acc8(a2, g2, val);  acc8(b2v, g2, val + 8);
    acc8(a3, g3, val);  acc8(b3v, g3, val + 8);

    __syncthreads();  // (A) all waves done MFMA-reading previous tap's LDS
    // --- stage w tap (swizzled 16B blocks): block index i -> row i>>3, blk i&7
    {
      const int r0 = tid >> 3, b0i = tid & 7;
      ((uint4*)wlds)[(r0 << 3) + (b0i ^ (r0 & 7))] = wv0;
      const int r1 = (tid + 256) >> 3;
      ((uint4*)wlds)[(r1 << 3) + (b0i ^ (r1 & 7))] = wv1;
    }
    // --- pack gathered vals to bf16 and write vlds rows (swizzled)
    {
      uint4 pka, pkb;
      pka.x = pk2bf(val[0], val[1]);
      pka.y = pk2bf(val[2], val[3]);
      pka.z = pk2bf(val[4], val[5]);
      pka.w = pk2bf(val[6], val[7]);
      pkb.x = pk2bf(val[8], val[9]);
      pkb.y = pk2bf(val[10], val[11]);
      pkb.z = pk2bf(val[12], val[13]);
      pkb.w = pk2bf(val[14], val[15]);
      const int rsw = pxi & 7;
      ((uint4*)vlds)[(pxi << 3) + (cq ^ rsw)] = pka;
      ((uint4*)vlds)[(pxi << 3) + ((cq + 4) ^ rsw)] = pkb;
    }
    __syncthreads();  // (B) wlds + vlds ready
    // --- MFMA: D[o-strip 16][px 64] += w[o][c] * val[c][px], K=64 in 2 steps
#pragma unroll
    for (int ks = 0; ks < 2; ++ks) {
      const int kb = (ks << 2) + lg;
      const int ra = oo0 + lr;
      const short8 afr = *(const short8*)&((const uint4*)wlds)[(ra << 3) + (kb ^ (ra & 7))];
#pragma unroll
      for (int j = 0; j < 4; ++j) {
        const int rb = (j << 4) + lr;
        const short8 bfr = *(const short8*)&((const uint4*)vlds)[(rb << 3) + (kb ^ (rb & 7))];
        acc[j] = __builtin_amdgcn_mfma_f32_16x16x32_bf16(afr, bfr, acc[j], 0, 0, 0);
      }
    }
  }

  // --- per-block IN partial stats (register-only; no atomics; deterministic)
  // plane-local pll = oo0 + lg*4 + q; sum over j (4 px-blocks) and 16-lane group.
#pragma unroll
  for (int q = 0; q < 4; ++q) {
    float s = acc[0][q] + acc[1][q] + acc[2][q] + acc[3][q];
    float s2 = fmaf(acc[0][q], acc[0][q],
               fmaf(acc[1][q], acc[1][q],
               fmaf(acc[2][q], acc[2][q], acc[3][q] * acc[3][q])));
#pragma unroll
    for (int m = 1; m < 16; m <<= 1) {
      s += __shfl_xor(s, m);
      s2 += __shfl_xor(s2, m);
    }
    if (lr == 0) {
      const int pll = oo0 + (lg << 2) + q;
      ((float2*)pstats2)[(size_t)t * 64 + pll] = make_float2(s, s2);
    }
  }

  // --- epilogue: transpose through (now dead) LDS -> coalesced float4 stores
  __syncthreads();  // all MFMA reads of smem done
  float* fsm = (float*)smem;  // [64 o][64 px] f32 = 16 KB
#pragma unroll
  for (int j = 0; j < 4; ++j)
#pragma unroll
    for (int q = 0; q < 4; ++q)
      fsm[(oo0 + (lg << 2) + q) * 64 + (j << 4) + lr] = acc[j][q];
  __syncthreads();
  {
    const float4* fsm4 = (const float4*)fsm;
    float* prebase = pre + (size_t)b * O_ * HW_ + p0;
#pragma unroll
    for (int i = 0; i < 4; ++i) {
      const int f = tid + (i << 8);
      const int o = f >> 4;
      const int px4 = (f & 15) << 2;
      *(float4*)&prebase[(size_t)o * HW_ + px4] = fsm4[f];
    }
  }
}

// ---------------- K4: finalize stats from per-tile partials ----------------
__global__ __launch_bounds__(256) void k4_fin(const float* __restrict__ pstats2,
                                              float* __restrict__ stats) {
  const int pl = blockIdx.x;  // 0..127 = b*O + o
  const int b = pl >> 6, o = pl & 63;
  const float2* src = (const float2*)pstats2 + (size_t)b * 576 * 64 + o;
  float s = 0.f, s2 = 0.f;
  for (int tt = threadIdx.x; tt < 576; tt += 256) {
    const float2 v = src[(size_t)tt * 64];
    s += v.x;
    s2 += v.y;
  }
#pragma unroll
  for (int m = 1; m < 64; m <<= 1) {
    s += __shfl_xor(s, m);
    s2 += __shfl_xor(s2, m);
  }
  __shared__ float ls[4], ls2[4];
  const int wid = threadIdx.x >> 6;
  if ((threadIdx.x & 63) == 0) { ls[wid] = s; ls2[wid] = s2; }
  __syncthreads();
  if (threadIdx.x == 0) {
    const float ts = ls[0] + ls[1] + ls[2] + ls[3];
    const float ts2 = ls2[0] + ls2[1] + ls2[2] + ls2[3];
    const float inv = 1.f / (float)HW_;
    const float mu = ts * inv;
    const float var = fmaxf(fmaf(-mu, mu, ts2 * inv), 0.f);
    stats[pl * 2] = mu;
    stats[pl * 2 + 1] = rsqrtf(var + EPS_);
  }
}

// ---------------- K5: apply instance norm + ReLU ----------------
__global__ __launch_bounds__(256) void k5_norm(const float* __restrict__ pre,
                                               const float* __restrict__ stats,
                                               float* __restrict__ out) {
  const int i4 = blockIdx.x * 256 + threadIdx.x;
  const int plane = i4 / 9216;
  const float mu = stats[plane * 2];
  const float rs = stats[plane * 2 + 1];
  float4 v = ((const float4*)pre)[i4];
  v.x = fmaxf((v.x - mu) * rs, 0.f);
  v.y = fmaxf((v.y - mu) * rs, 0.f);
  v.z = fmaxf((v.z - mu) * rs, 0.f);
  v.w = fmaxf((v.w - mu) * rs, 0.f);
  ((float4*)out)[i4] = v;
}

extern "C" void kernel_launch(void* const* d_in, const int* in_sizes, int n_in,
                              void* d_out, int out_size, void* d_ws, size_t ws_size,
                              hipStream_t stream) {
  const float* x = (const float*)d_in[0];
  const float* dw_w = (const float*)d_in[1];
  const float* dw_b = (const float*)d_in[2];
  const float* bn_g = (const float*)d_in[3];
  const float* bn_b = (const float*)d_in[4];
  const float* bn_m = (const float*)d_in[5];
  const float* bn_v = (const float*)d_in[6];
  const float* pw_w = (const float*)d_in[7];
  const float* pw_b = (const float*)d_in[8];
  const float* dcn_w = (const float*)d_in[9];
  float* out = (float*)d_out;

  // workspace layout (floats)
  float* ws = (float*)d_ws;
  float* h = ws;                                  // B*C*HW = 4718592 (reused as pre)
  float* om = h + (size_t)B_ * C_ * HW_;          // B*27*HW = 1990656
  unsigned short* wT2 = (unsigned short*)(om + (size_t)B_ * 27 * HW_);  // 36864 u16
  float* stats = (float*)(wT2 + (size_t)K_ * O_ * C_);  // 256
  if (ws_size < (size_t)(4718592 + 1990656 + 18432 + 256) * sizeof(float)) return;
  float* pre = h;  // h is dead after k2; reuse for pre-norm output
  // xR (gather-layout bf16, 9.4 MB) + pstats2 (590 KB) live in d_out:
  // both fully overwritten by k5 at the end.
  unsigned short* xR = (unsigned short*)d_out;
  float* pstats2 = (float*)d_out + 2359296;  // after xR (2359296 floats-worth)

  k0_wt<<<dim3(144), dim3(256), 0, stream>>>(dcn_w, wT2);
  k1b_t<<<dim3(HW_ / 256, B_), dim3(256), 0, stream>>>(x, xR);
  k1_dw<<<dim3(HW_ / 256, B_ * C_), dim3(256), 0, stream>>>(x, dw_w, dw_b, bn_g, bn_b,
                                                            bn_m, bn_v, h);
  k2_pw<<<dim3(HW_ / 256, B_), dim3(256), 0, stream>>>(h, pw_w, pw_b, om);
  k3_dcn<<<dim3(B_ * HW_ / 64), dim3(256), 0, stream>>>(xR, om, wT2, pre, pstats2);
  k4_fin<<<dim3(B_ * O_), dim3(256), 0, stream>>>(pstats2, stats);
  k5_norm<<<dim3(B_ * O_ * HW_ / 4 / 256), dim3(256), 0, stream>>>(pre, stats, out);
}